// Round 1
// baseline (299.223 us; speedup 1.0000x reference)
//
#include <hip/hip_runtime.h>
#include <hip/hip_bf16.h>
#include <math.h>

// Problem constants (from reference): B=8, C=256, H=W=128
#define NPLANE 2048      // B*C
#define HW     16384     // H*W
#define HH     128
#define WW     128
#define SLOPE  0.01f
#define EPS    1e-5f

// ---------------------------------------------------------------------------
// Kernel 1: per-(b,c) plane mean.  One block per plane, 256 threads.
// ---------------------------------------------------------------------------
__global__ __launch_bounds__(256) void k_plane_mean(const float* __restrict__ x,
                                                    float* __restrict__ p) {
    const int plane = blockIdx.x;
    const float4* x4 = (const float4*)(x + (size_t)plane * HW);
    float s = 0.f;
#pragma unroll
    for (int i = 0; i < 16; ++i) {
        float4 v = x4[i * 256 + threadIdx.x];
        s += (v.x + v.y) + (v.z + v.w);
    }
#pragma unroll
    for (int off = 32; off; off >>= 1) s += __shfl_down(s, off, 64);
    __shared__ float red[4];
    const int wave = threadIdx.x >> 6, lane = threadIdx.x & 63;
    if (lane == 0) red[wave] = s;
    __syncthreads();
    if (threadIdx.x == 0) {
        float t = (red[0] + red[1]) + (red[2] + red[3]);
        p[plane] = t * (1.f / (float)HW);
    }
}

// ---------------------------------------------------------------------------
// Kernel 2: squeeze-excite attention.  Single block, 256 threads.
//   h[b,j] = leaky(sum_k p[b,k] * w1[j,k])      (8 x 64)
//   a[b,c] = sigmoid(sum_j h[b,j] * w2[c,j])    (8 x 256)
// ---------------------------------------------------------------------------
__global__ __launch_bounds__(256) void k_attn(const float* __restrict__ p,
                                              const float* __restrict__ w1,
                                              const float* __restrict__ w2,
                                              float* __restrict__ a) {
    __shared__ float ps[NPLANE];
    __shared__ float hs[512];
    for (int i = threadIdx.x; i < NPLANE; i += 256) ps[i] = p[i];
    __syncthreads();
    for (int t = threadIdx.x; t < 512; t += 256) {
        const int b = t >> 6, j = t & 63;
        const float* prow = ps + b * 256;
        const float* wrow = w1 + j * 256;
        float acc = 0.f;
#pragma unroll 8
        for (int k = 0; k < 256; ++k) acc += prow[k] * wrow[k];
        hs[b * 64 + j] = acc > 0.f ? acc : SLOPE * acc;
    }
    __syncthreads();
    for (int t = threadIdx.x; t < NPLANE; t += 256) {
        const int b = t >> 8, c = t & 255;
        const float* hrow = hs + b * 64;
        const float* wrow = w2 + c * 64;
        float acc = 0.f;
#pragma unroll 8
        for (int k = 0; k < 64; ++k) acc += hrow[k] * wrow[k];
        a[t] = 1.f / (1.f + __expf(-acc));
    }
}

// ---------------------------------------------------------------------------
// Kernel 3: fused scale -> depthwise 3x3 conv + bias -> instance norm -> leaky.
// One block per plane; plane staged in LDS (64 KiB); thread t owns column
// (t&127), rows [(t>>7)*64, +64).  Register sliding window: 3 LDS reads/pixel.
// conv(a*x) == a*conv(x), so the attention scale folds into the epilogue.
// ---------------------------------------------------------------------------
__global__ __launch_bounds__(256) void k_main(const float* __restrict__ x,
                                              const float* __restrict__ rw,
                                              const float* __restrict__ rb,
                                              const float* __restrict__ a,
                                              float* __restrict__ out) {
    __shared__ float tile[HW];           // exactly 64 KiB
    const int plane = blockIdx.x;
    const int ch = plane & 255;

    // stage plane into LDS, coalesced float4
    {
        const float4* x4 = (const float4*)(x + (size_t)plane * HW);
        float4* t4 = (float4*)tile;
#pragma unroll
        for (int i = 0; i < 16; ++i) t4[i * 256 + threadIdx.x] = x4[i * 256 + threadIdx.x];
    }

    // per-channel conv weights / bias / attention scale (wave-uniform)
    float w0 = rw[ch * 9 + 0], w1 = rw[ch * 9 + 1], w2 = rw[ch * 9 + 2];
    float w3 = rw[ch * 9 + 3], w4 = rw[ch * 9 + 4], w5 = rw[ch * 9 + 5];
    float w6 = rw[ch * 9 + 6], w7 = rw[ch * 9 + 7], w8 = rw[ch * 9 + 8];
    const float bias = rb[ch];
    const float av = a[plane];

    __syncthreads();

    const int c = threadIdx.x & 127;
    const int r0 = (threadIdx.x >> 7) * 64;

    float l0, m0, q0, l1, m1, q1, l2, m2, q2;

#define LOADROW(row, L, M, Q)                                         \
    do {                                                              \
        int _r = (row);                                               \
        if (_r < 0 || _r > 127) { L = 0.f; M = 0.f; Q = 0.f; }        \
        else {                                                        \
            const float* rp = tile + _r * WW;                         \
            M = rp[c];                                                \
            L = (c > 0)   ? rp[c - 1] : 0.f;                          \
            Q = (c < 127) ? rp[c + 1] : 0.f;                          \
        }                                                             \
    } while (0)

    LOADROW(r0 - 1, l0, m0, q0);
    LOADROW(r0,     l1, m1, q1);

    float y[64];
    float s = 0.f, sq = 0.f;
#pragma unroll
    for (int j = 0; j < 64; ++j) {
        LOADROW(r0 + j + 1, l2, m2, q2);
        float conv = w0 * l0 + w1 * m0 + w2 * q0
                   + w3 * l1 + w4 * m1 + w5 * q1
                   + w6 * l2 + w7 * m2 + w8 * q2;
        float v = conv * av + bias;
        y[j] = v;
        s += v;
        sq += v * v;
        l0 = l1; m0 = m1; q0 = q1;
        l1 = l2; m1 = m2; q1 = q2;
    }
#undef LOADROW

    // block reduction of sum / sumsq
#pragma unroll
    for (int off = 32; off; off >>= 1) {
        s  += __shfl_down(s,  off, 64);
        sq += __shfl_down(sq, off, 64);
    }
    __syncthreads();            // conv reads of tile are done; safe to reuse
    const int wave = threadIdx.x >> 6, lane = threadIdx.x & 63;
    if (lane == 0) { tile[wave] = s; tile[4 + wave] = sq; }
    __syncthreads();
    const float S  = (tile[0] + tile[1]) + (tile[2] + tile[3]);
    const float SQ = (tile[4] + tile[5]) + (tile[6] + tile[7]);
    const float mean = S * (1.f / (float)HW);
    const float var  = SQ * (1.f / (float)HW) - mean * mean;
    const float rstd = rsqrtf(var + EPS);

    float* op = out + (size_t)plane * HW;
#pragma unroll
    for (int j = 0; j < 64; ++j) {
        float v = (y[j] - mean) * rstd;
        v = v > 0.f ? v : SLOPE * v;
        op[(r0 + j) * WW + c] = v;
    }
}

// ---------------------------------------------------------------------------
extern "C" void kernel_launch(void* const* d_in, const int* in_sizes, int n_in,
                              void* d_out, int out_size, void* d_ws, size_t ws_size,
                              hipStream_t stream) {
    const float* x  = (const float*)d_in[0];
    const float* w1 = (const float*)d_in[1];   // [64,256]
    const float* w2 = (const float*)d_in[2];   // [256,64]
    const float* rw = (const float*)d_in[3];   // [256,1,3,3]
    const float* rb = (const float*)d_in[4];   // [256]
    float* out = (float*)d_out;

    float* p = (float*)d_ws;        // 2048 floats
    float* a = p + NPLANE;          // 2048 floats

    k_plane_mean<<<NPLANE, 256, 0, stream>>>(x, p);
    k_attn<<<1, 256, 0, stream>>>(p, w1, w2, a);
    k_main<<<NPLANE, 256, 0, stream>>>(x, rw, rb, a, out);
}